// Round 4
// baseline (671.232 us; speedup 1.0000x reference)
//
#include <hip/hip_runtime.h>
#include <math.h>

typedef __bf16 bf16;
typedef __bf16 bf16x8 __attribute__((ext_vector_type(8)));
typedef __bf16 bf16x4 __attribute__((ext_vector_type(4)));
typedef __bf16 bf16x2 __attribute__((ext_vector_type(2)));
typedef float f32x4 __attribute__((ext_vector_type(4)));

#define B_ROWS 32768
#define PSZ 8192          // panel: 256 n-rows x 32 k, bf16 elems (16 KB)
#define PBYTES 16384

// panel-index bases in ws (panel-major, n-major within panel, UNSWIZZLED)
#define PB_PW0   0    // 4 panels  (K=128)
#define PB_PW1   4    // 8
#define PB_PW2   12   // 16
#define PB_RW1   28   // 6*16
#define PB_LPW1  124  // 3*8
#define PB_LPW2  148  // 3*8
#define PB_FAW1  172  // 24
#define PB_FAW2  196  // 8   (total 204 panels = 3.34 MB)

// Panel image: dst[n*32 + k'] = src[(kp*32 + k')*256 + n]  (fp32->bf16).
__global__ void wprep_kernel(const float* __restrict__ pW0, const float* __restrict__ pW1,
                             const float* __restrict__ pW2, const float* __restrict__ rW1,
                             const float* __restrict__ lpW1, const float* __restrict__ lpW2,
                             const float* __restrict__ faW1, const float* __restrict__ faW2,
                             bf16* __restrict__ ws) {
  int p = blockIdx.x;
  const float* src; int kp;
  if (p < 4)        { src = pW0;  kp = p; }
  else if (p < 12)  { src = pW1;  kp = p - 4; }
  else if (p < 28)  { src = pW2;  kp = p - 12; }
  else if (p < 124) { int q = p - 28;  src = rW1  + (size_t)(q >> 4) * 512 * 256; kp = q & 15; }
  else if (p < 148) { int q = p - 124; src = lpW1 + (size_t)(q >> 3) * 256 * 256; kp = q & 7; }
  else if (p < 172) { int q = p - 148; src = lpW2 + (size_t)(q >> 3) * 256 * 256; kp = q & 7; }
  else if (p < 196) { src = faW1; kp = p - 172; }
  else              { src = faW2; kp = p - 196; }
  bf16* dst = ws + (size_t)p * PSZ;
  int n = threadIdx.x;  // 256 threads, one n-row each
#pragma unroll
  for (int kb = 0; kb < 32; kb += 8) {
    bf16x8 v;
#pragma unroll
    for (int j = 0; j < 8; j++)
      v[j] = (bf16)src[(size_t)(kp * 32 + kb + j) * 256 + n];  // coalesced over n
    *(bf16x8*)(dst + n * 32 + kb) = v;
  }
}

#define FENCE asm volatile("" ::: "memory")
#define BAR()  do { FENCE; __builtin_amdgcn_s_barrier(); FENCE; } while (0)
#define BARP() do { asm volatile("s_waitcnt lgkmcnt(0)" ::: "memory"); \
                    __builtin_amdgcn_s_barrier(); FENCE; } while (0)
// Dataflow-tied counted waits (NO sched_barrier wall): the wait redefines the
// B slot it guards, so consuming MFMAs cannot hoist above it (rule #18), while
// the scheduler stays free to move independent work across the wait.
#define VWB2(N, B) asm volatile("s_waitcnt vmcnt(" #N ")" \
                                : "+v"(B[0]), "+v"(B[1]) :: "memory")
#define VWB4(N, B) asm volatile("s_waitcnt vmcnt(" #N ")" \
                                : "+v"(B[0]), "+v"(B[1]), "+v"(B[2]), "+v"(B[3]) :: "memory")

// 2 x global_load_dwordx4 of one 32-col B sub-panel into pinned registers.
__device__ __forceinline__ void ld2(bf16x8& d0, bf16x8& d1, const void* addr) {
  asm volatile("global_load_dwordx4 %0, %2, off\n\t"
               "global_load_dwordx4 %1, %2, off offset:1024"
               : "=&v"(d0), "=&v"(d1)
               : "v"(addr));
}
// 4 x global_load_dwordx4 of one 64-col B sub-panel into pinned registers.
__device__ __forceinline__ void ld4(bf16x8& d0, bf16x8& d1, bf16x8& d2, bf16x8& d3,
                                    const void* addr) {
  asm volatile("global_load_dwordx4 %0, %4, off\n\t"
               "global_load_dwordx4 %1, %4, off offset:1024\n\t"
               "global_load_dwordx4 %2, %4, off offset:2048\n\t"
               "global_load_dwordx4 %3, %4, off offset:3072"
               : "=&v"(d0), "=&v"(d1), "=&v"(d2), "=&v"(d3)
               : "v"(addr));
}

// 32-row blocks (grid 1024). Occupancy/regalloc lesson (R1-R3): any
// annotation expressing min waves/EU >= 4 drives the gfx950 allocator to
// the 8-waves/EU step (64-VGPR cap) and it SPILLS the pinned-register
// pipeline (~320 B/thread scratch, WRITE_SIZE 201 MB). The ONLY proven
// no-spill config is amdgpu_waves_per_eu(2,2) (R0 baseline: VGPR=128,
// zero scratch). With VGPR=128 the HARDWARE fits 4 waves/EU, and the LDS
// pad to 55,296 B caps at 2 blocks/CU -> 16 waves/CU runtime occupancy
// (2x the 426us baseline) without the allocator ever seeing a high
// occupancy target.
// 512 threads = 8 waves. Routing pairs (p, p+1) share SRC: merged 512-col
// GEMM, waves 0-3 = p's cols, waves 4-7 = (p+1)'s cols, wave tile 32x64
// (8 MFMA/phase). lp/fa/proj keep the 32x32-tile path. B always
// direct-from-L2 via pinned asm loads.
__global__ void __launch_bounds__(512)
__attribute__((amdgpu_waves_per_eu(2, 2)))
fused_kernel(const float* __restrict__ xf, const float* __restrict__ xm,
                  const float* __restrict__ xc,
                  const float* __restrict__ pb0, const float* __restrict__ pb1v,
                  const float* __restrict__ pb2v,
                  const float* __restrict__ rb1, const float* __restrict__ rW2,
                  const float* __restrict__ rb2,
                  const float* __restrict__ lpb1, const float* __restrict__ lpb2,
                  const float* __restrict__ lng, const float* __restrict__ lnb,
                  const float* __restrict__ fab1, const float* __restrict__ fab2,
                  const float* __restrict__ fng, const float* __restrict__ fnb,
                  const bf16* __restrict__ ws, float* __restrict__ out) {
  __shared__ bf16 feats[3][32][256];   // 48 KB
  __shared__ char scratch[5120];       // apan/lnred union (2 KB used) + occupancy pad
  __shared__ float w_route[6][32];     // 768 B

  const int t = threadIdx.x;
  const int lane = t & 63;
  const int cg = t >> 6;               // wave id, 0..7
  const int lr = lane & 15;
  const int lk = lane >> 4;
  const int r0 = blockIdx.x * 32;

  char* featsB = (char*)&feats[0][0][0];
  char* apanB  = scratch;
  float (*lnred)[2][32] = (float (*)[2][32])scratch;  // [cg][sum/sq][row]

  f32x4 acc[8];  // merged routing: [rt*4+ct] rt<2,ct<4 ; narrow path: [rt*2+ct] ct<2
  auto zacc8 = [&]() {
#pragma unroll
    for (int i = 0; i < 8; i++) acc[i] = (f32x4){0.f, 0.f, 0.f, 0.f};
  };
  auto zacc4 = [&]() {
#pragma unroll
    for (int i = 0; i < 4; i++) acc[i] = (f32x4){0.f, 0.f, 0.f, 0.f};
  };

  auto mf = [&](bf16x8* Av, bf16x8* Bv) {   // 32x32 tile: 4 MFMA
    __builtin_amdgcn_s_setprio(1);
#pragma unroll
    for (int rt = 0; rt < 2; rt++)
#pragma unroll
      for (int ct = 0; ct < 2; ct++)
        acc[rt * 2 + ct] = __builtin_amdgcn_mfma_f32_16x16x32_bf16(Av[rt], Bv[ct], acc[rt * 2 + ct], 0, 0, 0);
    __builtin_amdgcn_s_setprio(0);
  };
  auto mfR = [&](bf16x8* Av, bf16x8* Bv) {  // 32x64 tile: 8 MFMA
    __builtin_amdgcn_s_setprio(1);
#pragma unroll
    for (int rt = 0; rt < 2; rt++)
#pragma unroll
      for (int ct = 0; ct < 4; ct++)
        acc[rt * 4 + ct] = __builtin_amdgcn_mfma_f32_16x16x32_bf16(Av[rt], Bv[ct], acc[rt * 4 + ct], 0, 0, 0);
    __builtin_amdgcn_s_setprio(0);
  };

  const int SRCa[6] = {0, 0, 1, 1, 2, 2};
  const int TGTa[6] = {1, 2, 0, 2, 0, 1};

  // Merged routing-pair GEMM (p0 even): n=16 phases, wave tile 32x64,
  // B distance-2 pinned (8 loads in flight, dataflow-tied vmcnt(4)).
  auto gemmR = [&](int p0) {
    const int pp = p0 + (cg >> 2);
    const char* Wb = (const char*)(ws + (size_t)(PB_RW1 + pp * 16) * PSZ)
                     + (((cg & 3) * 64 + lr) * 64 + lk * 16);
    const int lS = SRCa[p0];
    const int lT = TGTa[pp];
    bf16x8 Ba[4], Bb[4], Aa[2], Ab[2];
    auto ldB = [&](int s, bf16x8* Bv) {
      ld4(Bv[0], Bv[1], Bv[2], Bv[3], Wb + (size_t)s * PBYTES);
    };
    auto readA = [&](int s, bf16x8* Av) {
      int lvl = (s < 8) ? lS : lT;
      int q = (s & 7) * 4;
#pragma unroll
      for (int rt = 0; rt < 2; rt++) {
        int r = rt * 16 + lr;
        Av[rt] = *(const bf16x8*)(featsB + ((lvl * 32 + r) << 9) + (((q + lk) ^ (r & 7)) << 4));
      }
    };
    ldB(0, Ba); ldB(1, Bb);   // 8 loads in flight
    readA(0, Aa);
    int s = 0;
#pragma unroll 1
    for (; s < 14; s += 2) {
      readA(s + 1, Ab); VWB4(4, Ba); mfR(Aa, Ba); ldB(s + 2, Ba);
      readA(s + 2, Aa); VWB4(4, Bb); mfR(Ab, Bb); ldB(s + 3, Bb);
    }
    // tail: phases 14 (Aa,Ba), 15 (Ab,Bb)
    readA(15, Ab); VWB4(4, Ba); mfR(Aa, Ba);
    VWB4(0, Bb); mfR(Ab, Bb);
  };

  // Merged routing epilogue: produces gates for p0 (waves 0-3) and p0+1 (4-7).
  auto routing_epi2 = [&](int p0) {
    const int pp = p0 + (cg >> 2);
    float part[2][4] = {{0}};
#pragma unroll
    for (int ct = 0; ct < 4; ct++) {
      int col = (cg & 3) * 64 + ct * 16 + lr;
      float b1 = rb1[pp * 256 + col];
      float w2 = rW2[pp * 256 + col];
#pragma unroll
      for (int rt = 0; rt < 2; rt++)
#pragma unroll
        for (int e = 0; e < 4; e++)
          part[rt][e] += fmaxf(acc[rt * 4 + ct][e] + b1, 0.f) * w2;
    }
#pragma unroll
    for (int m = 1; m < 16; m <<= 1)
#pragma unroll
      for (int rt = 0; rt < 2; rt++)
#pragma unroll
        for (int e = 0; e < 4; e++)
          part[rt][e] += __shfl_xor(part[rt][e], m, 64);
    if (lr == 0)
#pragma unroll
      for (int rt = 0; rt < 2; rt++)
#pragma unroll
        for (int e = 0; e < 4; e++)
          lnred[cg][0][rt * 16 + lk * 4 + e] = part[rt][e];
    BARP();
    if (t < 64) {
      int pi = t >> 5, r = t & 31;
      float s = rb2[p0 + pi];
#pragma unroll
      for (int g = 0; g < 4; g++) s += lnred[pi * 4 + g][0][r];
      w_route[p0 + pi][r] = 1.f / (1.f + expf(-s));
    }
    BARP();
  };

  // Narrow GEMM (lp/fa): wave tile 32x32, B distance-4 pinned, vmcnt(6).
  auto gemm = [&](const bf16* W, int n, int l0, int l1, int l2) {
    const char* Wb = (const char*)W + ((cg * 32 + lr) * 64 + lk * 16);
    bf16x8 B0[2], B1[2], B2[2], B3[2], A0[2], A1[2];
    auto ldB = [&](int s, bf16x8* Bv) {
      ld2(Bv[0], Bv[1], Wb + (size_t)s * PBYTES);
    };
    auto readA = [&](int s, bf16x8* Av) {
      int lvl = (s >= 16) ? l2 : ((s >= 8) ? l1 : l0);
      int q = (s & 7) * 4;
#pragma unroll
      for (int rt = 0; rt < 2; rt++) {
        int r = rt * 16 + lr;
        Av[rt] = *(const bf16x8*)(featsB + ((lvl * 32 + r) << 9) + (((q + lk) ^ (r & 7)) << 4));
      }
    };
    ldB(0, B0); ldB(1, B1); ldB(2, B2); ldB(3, B3);   // 8 loads in flight
    readA(0, A0);
    int s = 0;
#pragma unroll 1
    for (; s < n - 4; s += 4) {
      readA(s + 1, A1); VWB2(6, B0); mf(A0, B0); ldB(s + 4, B0);
      readA(s + 2, A0); VWB2(6, B1); mf(A1, B1); ldB(s + 5, B1);
      readA(s + 3, A1); VWB2(6, B2); mf(A0, B2); ldB(s + 6, B2);
      readA(s + 4, A0); VWB2(6, B3); mf(A1, B3); ldB(s + 7, B3);
    }
    readA(s + 1, A1); VWB2(6, B0); mf(A0, B0);
    readA(s + 2, A0); VWB2(4, B1); mf(A1, B1);
    readA(s + 3, A1); VWB2(2, B2); mf(A0, B2);
    VWB2(0, B3); mf(A1, B3);
  };

  // Projection GEMM: A = x (fp32 global) staged through apan; B direct.
  auto gemm_x = [&](const bf16* W, int n, const float* X, int Kx) {
    const char* Wb = (const char*)W + ((cg * 32 + lr) * 64 + lk * 16);
#pragma unroll 1
    for (int s = 0; s < n; s++) {
      bf16x8 b[2];
#pragma unroll
      for (int ct = 0; ct < 2; ct++)
        b[ct] = *(const bf16x8*)(Wb + (size_t)s * PBYTES + ct * 1024);
      int rr = t >> 4, c0 = (t & 15) * 2;
      float2 xv = *(const float2*)(X + (size_t)(r0 + rr) * Kx + s * 32 + c0);
      BAR();
      bf16x2 v;
      v[0] = (bf16)xv.x; v[1] = (bf16)xv.y;
      int cb = c0 >> 3;
      *(bf16x2*)(apanB + (rr << 6) + ((cb ^ ((rr >> 1) & 3)) << 4) + (c0 & 7) * 2) = v;
      BARP();
      bf16x8 a[2];
#pragma unroll
      for (int rt = 0; rt < 2; rt++) {
        int r = rt * 16 + lr;
        a[rt] = *(const bf16x8*)(apanB + (r << 6) + ((lk ^ ((r >> 1) & 3)) << 4));
      }
      mf(a, b);
    }
  };

  auto stF = [&](int lvl, int r, int c, float v) {
    *(bf16*)(featsB + ((lvl * 32 + r) << 9) +
             ((((c >> 3) ^ (r & 7))) << 4) + (c & 7) * 2) = (bf16)v;
  };
  auto epi_bias_store = [&](const float* bias, int lvl, bool do_relu) {
    BAR();
#pragma unroll
    for (int ct = 0; ct < 2; ct++) {
      int col = cg * 32 + ct * 16 + lr;
      float bv = bias[col];
#pragma unroll
      for (int rt = 0; rt < 2; rt++)
#pragma unroll
        for (int e = 0; e < 4; e++) {
          float v = acc[rt * 2 + ct][e] + bv;
          if (do_relu) v = fmaxf(v, 0.f);
          stF(lvl, rt * 16 + lk * 4 + e, col, v);
        }
    }
    BARP();
  };
  auto ln_epi = [&](const float* bias, const float* gamma, const float* beta, int lvl) {
    float sum[2][4] = {{0}}, sq[2][4] = {{0}};
#pragma unroll
    for (int ct = 0; ct < 2; ct++) {
      int col = cg * 32 + ct * 16 + lr;
      float bv = bias[col];
#pragma unroll
      for (int rt = 0; rt < 2; rt++)
#pragma unroll
        for (int e = 0; e < 4; e++) {
          float v = acc[rt * 2 + ct][e] + bv;
          acc[rt * 2 + ct][e] = v;
          sum[rt][e] += v; sq[rt][e] += v * v;
        }
    }
#pragma unroll
    for (int m = 1; m < 16; m <<= 1)
#pragma unroll
      for (int rt = 0; rt < 2; rt++)
#pragma unroll
      for (int e = 0; e < 4; e++) {
          sum[rt][e] += __shfl_xor(sum[rt][e], m, 64);
          sq[rt][e]  += __shfl_xor(sq[rt][e], m, 64);
        }
    if (lr == 0)
#pragma unroll
      for (int rt = 0; rt < 2; rt++)
#pragma unroll
        for (int e = 0; e < 4; e++) {
          int r = rt * 16 + lk * 4 + e;
          lnred[cg][0][r] = sum[rt][e];
          lnred[cg][1][r] = sq[rt][e];
        }
    BARP();
    if (t < 32) {
      float su = 0.f, sz = 0.f;
#pragma unroll
      for (int g = 0; g < 8; g++) { su += lnred[g][0][t]; sz += lnred[g][1][t]; }
      float mu = su * (1.f / 256.f);
      float ms = sz * (1.f / 256.f);
      lnred[0][0][t] = mu;
      lnred[0][1][t] = rsqrtf(ms - mu * mu + 1e-5f);
    }
    BARP();
#pragma unroll
    for (int rt = 0; rt < 2; rt++)
#pragma unroll
      for (int e = 0; e < 4; e++) {
        int r = rt * 16 + lk * 4 + e;
        float mu = lnred[0][0][r];
        float rstd = lnred[0][1][r];
#pragma unroll
        for (int ct = 0; ct < 2; ct++) {
          int col = cg * 32 + ct * 16 + lr;
          float v = (acc[rt * 2 + ct][e] - mu) * rstd * gamma[col] + beta[col];
          if (lvl >= 0) stF(lvl, r, col, v);
          else out[(size_t)(r0 + r) * 256 + col] = v;
        }
      }
    BARP();
  };

  // ---------------- schedule ----------------
  zacc4(); gemm_x(ws + PB_PW0 * PSZ, 4,  xf, 128); epi_bias_store(pb0, 0, false);
  zacc4(); gemm_x(ws + PB_PW1 * PSZ, 8,  xm, 256); epi_bias_store(pb1v, 1, false);
  zacc4(); gemm_x(ws + PB_PW2 * PSZ, 16, xc, 512); epi_bias_store(pb2v, 2, false);

  for (int it = 0; it < 3; it++) {
    for (int p0 = 0; p0 < 6; p0 += 2) {
      zacc8();
      gemmR(p0);
      routing_epi2(p0);
    }
    // upd = feats + segment_sum(w * src)  (in place, disjoint per thread)
    {
      int r = t >> 4, c0 = (t & 15) * 16;
      float w6[6];
#pragma unroll
      for (int p = 0; p < 6; p++) w6[p] = w_route[p][r];
#pragma unroll
      for (int ccx = 0; ccx < 16; ccx += 8) {
        int c = c0 + ccx;
        int chunk = (((c >> 3) ^ (r & 7)) << 4);
        char* a0 = featsB + ((0 * 32 + r) << 9) + chunk;
        char* a1 = featsB + ((1 * 32 + r) << 9) + chunk;
        char* a2 = featsB + ((2 * 32 + r) << 9) + chunk;
        bf16x8 f0 = *(bf16x8*)a0, f1 = *(bf16x8*)a1, f2 = *(bf16x8*)a2;
        bf16x8 u0, u1, u2;
#pragma unroll
        for (int i = 0; i < 8; i++) {
          float a = (float)f0[i], b = (float)f1[i], d = (float)f2[i];
          u0[i] = (bf16)(a + w6[2] * b + w6[4] * d);
          u1[i] = (bf16)(b + w6[0] * a + w6[5] * d);
          u2[i] = (bf16)(d + w6[1] * a + w6[3] * b);
        }
        *(bf16x8*)a0 = u0; *(bf16x8*)a1 = u1; *(bf16x8*)a2 = u2;
      }
      BARP();
    }
    for (int l = 0; l < 3; l++) {
      zacc4();
      gemm(ws + (PB_LPW1 + l * 8) * PSZ, 8, l, 0, 0);
      epi_bias_store(lpb1 + l * 256, l, true);
      zacc4();
      gemm(ws + (PB_LPW2 + l * 8) * PSZ, 8, l, 0, 0);
      ln_epi(lpb2 + l * 256, lng + l * 256, lnb + l * 256, l);
    }
  }

  zacc4();
  gemm(ws + PB_FAW1 * PSZ, 24, 0, 1, 2);
  epi_bias_store(fab1, 0, true);   // h4 -> feats[0] (feats dead)
  zacc4();
  gemm(ws + PB_FAW2 * PSZ, 8, 0, 0, 0);
  ln_epi(fab2, fng, fnb, -1);

  // w output (last iteration's gates): out[B*256 + p*B + row]
  if (t < 192) {
    int p = t >> 5, r = t & 31;
    out[(size_t)B_ROWS * 256 + (size_t)p * B_ROWS + r0 + r] = w_route[p][r];
  }
}

extern "C" void kernel_launch(void* const* d_in, const int* in_sizes, int n_in,
                              void* d_out, int out_size, void* d_ws, size_t ws_size,
                              hipStream_t stream) {
  const float* xf   = (const float*)d_in[0];
  const float* xm   = (const float*)d_in[1];
  const float* xc   = (const float*)d_in[2];
  const float* pW0  = (const float*)d_in[3];
  const float* pb0  = (const float*)d_in[4];
  const float* pW1  = (const float*)d_in[5];
  const float* pb1  = (const float*)d_in[6];
  const float* pW2  = (const float*)d_in[7];
  const float* pb2  = (const float*)d_in[8];
  const float* rW1  = (const float*)d_in[9];
  const float* rb1  = (const float*)d_in[10];
  const float* rW2  = (const float*)d_in[11];
  const float* rb2  = (const float*)d_in[12];
  const float* lpW1 = (const float*)d_in[13];
  const float* lpb1 = (const float*)d_in[14];
  const float* lpW2 = (const float*)d_in[15];
  const float* lpb2 = (const float*)d_in[16];
  const float* lng  = (const float*)d_in[17];
  const float* lnb  = (const float*)d_in[18];
  const float* faW1 = (const float*)d_in[19];
  const float* fab1 = (const float*)d_in[20];
  const float* faW2 = (const float*)d_in[21];
  const float* fab2 = (const float*)d_in[22];
  const float* fng  = (const float*)d_in[23];
  const float* fnb  = (const float*)d_in[24];
  (void)in_sizes; (void)n_in; (void)out_size; (void)ws_size;

  bf16* ws = (bf16*)d_ws;
  float* out = (float*)d_out;

  wprep_kernel<<<204, 256, 0, stream>>>(pW0, pW1, pW2, rW1, lpW1, lpW2, faW1, faW2, ws);
  fused_kernel<<<1024, 512, 0, stream>>>(xf, xm, xc, pb0, pb1, pb2, rb1, rW2, rb2,
                                         lpb1, lpb2, lng, lnb, fab1, fab2, fng, fnb,
                                         ws, out);
}

// Round 5
// 526.675 us; speedup vs baseline: 1.2745x; 1.2745x over previous
//
#include <hip/hip_runtime.h>
#include <math.h>

typedef __bf16 bf16;
typedef __bf16 bf16x8 __attribute__((ext_vector_type(8)));
typedef __bf16 bf16x4 __attribute__((ext_vector_type(4)));
typedef float f32x4 __attribute__((ext_vector_type(4)));

#define B_ROWS 32768
#define PSZ 8192          // panel: 256 n-rows x 32 k, bf16 elems (16 KB)
#define PBYTES 16384

// panel-index bases in ws (panel-major, n-major within panel, UNSWIZZLED)
#define PB_PW0   0    // 4 panels  (K=128)
#define PB_PW1   4    // 8
#define PB_PW2   12   // 16
#define PB_RW1   28   // 6*16
#define PB_LPW1  124  // 3*8
#define PB_LPW2  148  // 3*8
#define PB_FAW1  172  // 24
#define PB_FAW2  196  // 8   (total 204 panels = 3.34 MB)

// Panel image: dst[n*32 + k'] = src[(kp*32 + k')*256 + n]  (fp32->bf16).
__global__ void wprep_kernel(const float* __restrict__ pW0, const float* __restrict__ pW1,
                             const float* __restrict__ pW2, const float* __restrict__ rW1,
                             const float* __restrict__ lpW1, const float* __restrict__ lpW2,
                             const float* __restrict__ faW1, const float* __restrict__ faW2,
                             bf16* __restrict__ ws) {
  int p = blockIdx.x;
  const float* src; int kp;
  if (p < 4)        { src = pW0;  kp = p; }
  else if (p < 12)  { src = pW1;  kp = p - 4; }
  else if (p < 28)  { src = pW2;  kp = p - 12; }
  else if (p < 124) { int q = p - 28;  src = rW1  + (size_t)(q >> 4) * 512 * 256; kp = q & 15; }
  else if (p < 148) { int q = p - 124; src = lpW1 + (size_t)(q >> 3) * 256 * 256; kp = q & 7; }
  else if (p < 172) { int q = p - 148; src = lpW2 + (size_t)(q >> 3) * 256 * 256; kp = q & 7; }
  else if (p < 196) { src = faW1; kp = p - 172; }
  else              { src = faW2; kp = p - 196; }
  bf16* dst = ws + (size_t)p * PSZ;
  int n = threadIdx.x;  // 256 threads, one n-row each
#pragma unroll
  for (int kb = 0; kb < 32; kb += 8) {
    bf16x8 v;
#pragma unroll
    for (int j = 0; j < 8; j++)
      v[j] = (bf16)src[(size_t)(kp * 32 + kb + j) * 256 + n];  // coalesced over n
    *(bf16x8*)(dst + n * 32 + kb) = v;
  }
}

#define FENCE asm volatile("" ::: "memory")
#define BAR()  do { FENCE; __builtin_amdgcn_s_barrier(); FENCE; } while (0)
#define BARP() do { asm volatile("s_waitcnt lgkmcnt(0)" ::: "memory"); \
                    __builtin_amdgcn_s_barrier(); FENCE; } while (0)
// Dataflow-tied counted waits (NO sched_barrier wall): the wait redefines the
// B slot it guards, so consuming MFMAs cannot hoist above it (rule #18), while
// the scheduler stays free to move independent work across the wait.
#define VWB4(N, B) asm volatile("s_waitcnt vmcnt(" #N ")" \
                                : "+v"(B[0]), "+v"(B[1]), "+v"(B[2]), "+v"(B[3]) :: "memory")

// 4 x global_load_dwordx4 of one 64-col B sub-panel into pinned registers.
__device__ __forceinline__ void ld4(bf16x8& d0, bf16x8& d1, bf16x8& d2, bf16x8& d3,
                                    const void* addr) {
  asm volatile("global_load_dwordx4 %0, %4, off\n\t"
               "global_load_dwordx4 %1, %4, off offset:1024\n\t"
               "global_load_dwordx4 %2, %4, off offset:2048\n\t"
               "global_load_dwordx4 %3, %4, off offset:3072"
               : "=&v"(d0), "=&v"(d1), "=&v"(d2), "=&v"(d3)
               : "v"(addr));
}

// 32-row blocks, 256 threads = 4 waves (1 wave/EU), grid 1024.
// Occupancy strategy (R1-R4 ledger): amdgpu_waves_per_eu(2,2) is the ONLY
// attribute with proven-sane regalloc (R0: 128 VGPR, R4: 108, both
// spill-free; every min>=4 variant spilled at 64 VGPR). Its max=2/EU capped
// the old 8-wave block (2 waves/EU) at ONE resident block -> all waves
// barrier-locked together. A 4-wave block is 1 wave/EU, so TWO independent
// blocks co-reside under the same attribute: one block's MFMA phases hide
// the other's barrier/epilogue stalls.
// Each wave covers 64 cols (ct<4, acc[8], ld4 B double-buffer, vmcnt(4)).
// Routing pairs un-merged: 6 separate 256-col GEMMs (K=512), same MFMA and
// B-load totals as the merged form. B always direct-from-L2 via pinned asm.
__global__ void __launch_bounds__(256)
__attribute__((amdgpu_waves_per_eu(2, 2)))
fused_kernel(const float* __restrict__ xf, const float* __restrict__ xm,
                  const float* __restrict__ xc,
                  const float* __restrict__ pb0, const float* __restrict__ pb1v,
                  const float* __restrict__ pb2v,
                  const float* __restrict__ rb1, const float* __restrict__ rW2,
                  const float* __restrict__ rb2,
                  const float* __restrict__ lpb1, const float* __restrict__ lpb2,
                  const float* __restrict__ lng, const float* __restrict__ lnb,
                  const float* __restrict__ fab1, const float* __restrict__ fab2,
                  const float* __restrict__ fng, const float* __restrict__ fnb,
                  const bf16* __restrict__ ws, float* __restrict__ out) {
  __shared__ bf16 feats[3][32][256];   // 48 KB
  __shared__ char scratch[2048];       // apan[32][32] bf16 UNION lnred[4][2][32] f32
  __shared__ float w_route[6][32];     // 768 B

  const int t = threadIdx.x;           // 0..255
  const int lane = t & 63;
  const int cg = t >> 6;               // wave id, 0..3
  const int lr = lane & 15;
  const int lk = lane >> 4;
  const int r0 = blockIdx.x * 32;

  char* featsB = (char*)&feats[0][0][0];
  char* apanB  = scratch;
  float (*lnred)[2][32] = (float (*)[2][32])scratch;  // [cg][sum/sq][row]

  f32x4 acc[8];  // [rt*4+ct], rt<2 (rows), ct<4 (col tiles): 32 rows x 64 cols
  auto zacc8 = [&]() {
#pragma unroll
    for (int i = 0; i < 8; i++) acc[i] = (f32x4){0.f, 0.f, 0.f, 0.f};
  };

  auto mf = [&](bf16x8* Av, bf16x8* Bv) {   // 32x64 tile: 8 MFMA
    __builtin_amdgcn_s_setprio(1);
#pragma unroll
    for (int rt = 0; rt < 2; rt++)
#pragma unroll
      for (int ct = 0; ct < 4; ct++)
        acc[rt * 4 + ct] = __builtin_amdgcn_mfma_f32_16x16x32_bf16(Av[rt], Bv[ct], acc[rt * 4 + ct], 0, 0, 0);
    __builtin_amdgcn_s_setprio(0);
  };

  const int SRCa[6] = {0, 0, 1, 1, 2, 2};
  const int TGTa[6] = {1, 2, 0, 2, 0, 1};

  // Uniform pipelined GEMM: n even phases (K = n*32), B via ld4 distance-2
  // (8 loads in flight, dataflow-tied vmcnt(4)). A level: phases 0-7 -> l0,
  // 8-15 -> l1, 16-23 -> l2.
  auto gemm = [&](const char* Wb0, int n, int l0, int l1, int l2) {
    const char* Wb = Wb0 + ((cg * 64 + lr) * 64 + lk * 16);
    bf16x8 Ba[4], Bb[4], Aa[2], Ab[2];
    auto ldB = [&](int s, bf16x8* Bv) {
      ld4(Bv[0], Bv[1], Bv[2], Bv[3], Wb + (size_t)s * PBYTES);
    };
    auto readA = [&](int s, bf16x8* Av) {
      int lvl = (s >= 16) ? l2 : ((s >= 8) ? l1 : l0);
      int q = (s & 7) * 4;
#pragma unroll
      for (int rt = 0; rt < 2; rt++) {
        int r = rt * 16 + lr;
        Av[rt] = *(const bf16x8*)(featsB + ((lvl * 32 + r) << 9) + (((q + lk) ^ (r & 7)) << 4));
      }
    };
    ldB(0, Ba); ldB(1, Bb);   // 8 loads in flight
    readA(0, Aa);
    int s = 0;
#pragma unroll 1
    for (; s < n - 2; s += 2) {
      readA(s + 1, Ab); VWB4(4, Ba); mf(Aa, Ba); ldB(s + 2, Ba);
      readA(s + 2, Aa); VWB4(4, Bb); mf(Ab, Bb); ldB(s + 3, Bb);
    }
    // tail: phases n-2 (Aa,Ba), n-1 (Ab,Bb)
    readA(n - 1, Ab); VWB4(4, Ba); mf(Aa, Ba);
    VWB4(0, Bb); mf(Ab, Bb);
  };

  // Routing epilogue for one pair p: h=relu(acc+b1); dot with rW2 col; sigmoid.
  auto routing_epi = [&](int p) {
    float part[2][4] = {{0}};
#pragma unroll
    for (int ct = 0; ct < 4; ct++) {
      int col = cg * 64 + ct * 16 + lr;
      float b1 = rb1[p * 256 + col];
      float w2 = rW2[p * 256 + col];
#pragma unroll
      for (int rt = 0; rt < 2; rt++)
#pragma unroll
        for (int e = 0; e < 4; e++)
          part[rt][e] += fmaxf(acc[rt * 4 + ct][e] + b1, 0.f) * w2;
    }
#pragma unroll
    for (int m = 1; m < 16; m <<= 1)
#pragma unroll
      for (int rt = 0; rt < 2; rt++)
#pragma unroll
        for (int e = 0; e < 4; e++)
          part[rt][e] += __shfl_xor(part[rt][e], m, 64);
    if (lr == 0)
#pragma unroll
      for (int rt = 0; rt < 2; rt++)
#pragma unroll
        for (int e = 0; e < 4; e++)
          lnred[cg][0][rt * 16 + lk * 4 + e] = part[rt][e];
    BARP();
    if (t < 32) {
      float s = rb2[p];
#pragma unroll
      for (int g = 0; g < 4; g++) s += lnred[g][0][t];
      w_route[p][t] = 1.f / (1.f + expf(-s));
    }
    BARP();
  };

  // Projection GEMM: A = x (fp32 global) staged through apan; B direct.
  auto gemm_x = [&](const bf16* W, int n, const float* X, int Kx) {
    const char* Wb = (const char*)W + ((cg * 64 + lr) * 64 + lk * 16);
#pragma unroll 1
    for (int s = 0; s < n; s++) {
      bf16x8 b[4];
#pragma unroll
      for (int ct = 0; ct < 4; ct++)
        b[ct] = *(const bf16x8*)(Wb + (size_t)s * PBYTES + ct * 1024);
      int rr = t >> 3, c0 = (t & 7) * 4;
      float4 xv = *(const float4*)(X + (size_t)(r0 + rr) * Kx + s * 32 + c0);
      BAR();
      bf16x4 v;
      v[0] = (bf16)xv.x; v[1] = (bf16)xv.y; v[2] = (bf16)xv.z; v[3] = (bf16)xv.w;
      int cb = c0 >> 3;
      *(bf16x4*)(apanB + (rr << 6) + ((cb ^ ((rr >> 1) & 3)) << 4) + (c0 & 7) * 2) = v;
      BARP();
      bf16x8 a[2];
#pragma unroll
      for (int rt = 0; rt < 2; rt++) {
        int r = rt * 16 + lr;
        a[rt] = *(const bf16x8*)(apanB + (r << 6) + ((lk ^ ((r >> 1) & 3)) << 4));
      }
      mf(a, b);
    }
  };

  auto stF = [&](int lvl, int r, int c, float v) {
    *(bf16*)(featsB + ((lvl * 32 + r) << 9) +
             ((((c >> 3) ^ (r & 7))) << 4) + (c & 7) * 2) = (bf16)v;
  };
  auto epi_bias_store = [&](const float* bias, int lvl, bool do_relu) {
    BAR();
#pragma unroll
    for (int ct = 0; ct < 4; ct++) {
      int col = cg * 64 + ct * 16 + lr;
      float bv = bias[col];
#pragma unroll
      for (int rt = 0; rt < 2; rt++)
#pragma unroll
        for (int e = 0; e < 4; e++) {
          float v = acc[rt * 4 + ct][e] + bv;
          if (do_relu) v = fmaxf(v, 0.f);
          stF(lvl, rt * 16 + lk * 4 + e, col, v);
        }
    }
    BARP();
  };
  auto ln_epi = [&](const float* bias, const float* gamma, const float* beta, int lvl) {
    float sum[2][4] = {{0}}, sq[2][4] = {{0}};
#pragma unroll
    for (int ct = 0; ct < 4; ct++) {
      int col = cg * 64 + ct * 16 + lr;
      float bv = bias[col];
#pragma unroll
      for (int rt = 0; rt < 2; rt++)
#pragma unroll
        for (int e = 0; e < 4; e++) {
          float v = acc[rt * 4 + ct][e] + bv;
          acc[rt * 4 + ct][e] = v;
          sum[rt][e] += v; sq[rt][e] += v * v;
        }
    }
#pragma unroll
    for (int m = 1; m < 16; m <<= 1)
#pragma unroll
      for (int rt = 0; rt < 2; rt++)
#pragma unroll
        for (int e = 0; e < 4; e++) {
          sum[rt][e] += __shfl_xor(sum[rt][e], m, 64);
          sq[rt][e]  += __shfl_xor(sq[rt][e], m, 64);
        }
    if (lr == 0)
#pragma unroll
      for (int rt = 0; rt < 2; rt++)
#pragma unroll
        for (int e = 0; e < 4; e++) {
          int r = rt * 16 + lk * 4 + e;
          lnred[cg][0][r] = sum[rt][e];
          lnred[cg][1][r] = sq[rt][e];
        }
    BARP();
    if (t < 32) {
      float su = 0.f, sz = 0.f;
#pragma unroll
      for (int g = 0; g < 4; g++) { su += lnred[g][0][t]; sz += lnred[g][1][t]; }
      float mu = su * (1.f / 256.f);
      float ms = sz * (1.f / 256.f);
      lnred[0][0][t] = mu;
      lnred[0][1][t] = rsqrtf(ms - mu * mu + 1e-5f);
    }
    BARP();
#pragma unroll
    for (int rt = 0; rt < 2; rt++)
#pragma unroll
      for (int e = 0; e < 4; e++) {
        int r = rt * 16 + lk * 4 + e;
        float mu = lnred[0][0][r];
        float rstd = lnred[0][1][r];
#pragma unroll
        for (int ct = 0; ct < 4; ct++) {
          int col = cg * 64 + ct * 16 + lr;
          float v = (acc[rt * 4 + ct][e] - mu) * rstd * gamma[col] + beta[col];
          if (lvl >= 0) stF(lvl, r, col, v);
          else out[(size_t)(r0 + r) * 256 + col] = v;
        }
      }
    BARP();
  };

  // ---------------- schedule ----------------
  zacc8(); gemm_x(ws + PB_PW0 * PSZ, 4,  xf, 128); epi_bias_store(pb0, 0, false);
  zacc8(); gemm_x(ws + PB_PW1 * PSZ, 8,  xm, 256); epi_bias_store(pb1v, 1, false);
  zacc8(); gemm_x(ws + PB_PW2 * PSZ, 16, xc, 512); epi_bias_store(pb2v, 2, false);

  for (int it = 0; it < 3; it++) {
    for (int p = 0; p < 6; p++) {
      zacc8();
      gemm((const char*)(ws + (size_t)(PB_RW1 + p * 16) * PSZ), 16, SRCa[p], TGTa[p], 0);
      routing_epi(p);
    }
    // upd = feats + segment_sum(w * src)  (in place, disjoint per thread)
    {
      int r = t >> 3, c0 = (t & 7) * 32;
      float w6[6];
#pragma unroll
      for (int p = 0; p < 6; p++) w6[p] = w_route[p][r];
#pragma unroll
      for (int ccx = 0; ccx < 32; ccx += 8) {
        int c = c0 + ccx;
        int chunk = (((c >> 3) ^ (r & 7)) << 4);
        char* a0 = featsB + ((0 * 32 + r) << 9) + chunk;
        char* a1 = featsB + ((1 * 32 + r) << 9) + chunk;
        char* a2 = featsB + ((2 * 32 + r) << 9) + chunk;
        bf16x8 f0 = *(bf16x8*)a0, f1 = *(bf16x8*)a1, f2 = *(bf16x8*)a2;
        bf16x8 u0, u1, u2;
#pragma unroll
        for (int i = 0; i < 8; i++) {
          float a = (float)f0[i], b = (float)f1[i], d = (float)f2[i];
          u0[i] = (bf16)(a + w6[2] * b + w6[4] * d);
          u1[i] = (bf16)(b + w6[0] * a + w6[5] * d);
          u2[i] = (bf16)(d + w6[1] * a + w6[3] * b);
        }
        *(bf16x8*)a0 = u0; *(bf16x8*)a1 = u1; *(bf16x8*)a2 = u2;
      }
      BARP();
    }
    for (int l = 0; l < 3; l++) {
      zacc8();
      gemm((const char*)(ws + (size_t)(PB_LPW1 + l * 8) * PSZ), 8, l, 0, 0);
      epi_bias_store(lpb1 + l * 256, l, true);
      zacc8();
      gemm((const char*)(ws + (size_t)(PB_LPW2 + l * 8) * PSZ), 8, l, 0, 0);
      ln_epi(lpb2 + l * 256, lng + l * 256, lnb + l * 256, l);
    }
  }

  zacc8();
  gemm((const char*)(ws + (size_t)PB_FAW1 * PSZ), 24, 0, 1, 2);
  epi_bias_store(fab1, 0, true);   // h4 -> feats[0] (feats dead)
  zacc8();
  gemm((const char*)(ws + (size_t)PB_FAW2 * PSZ), 8, 0, 0, 0);
  ln_epi(fab2, fng, fnb, -1);

  // w output (last iteration's gates): out[B*256 + p*B + row]
  if (t < 192) {
    int p = t >> 5, r = t & 31;
    out[(size_t)B_ROWS * 256 + (size_t)p * B_ROWS + r0 + r] = w_route[p][r];
  }
}

extern "C" void kernel_launch(void* const* d_in, const int* in_sizes, int n_in,
                              void* d_out, int out_size, void* d_ws, size_t ws_size,
                              hipStream_t stream) {
  const float* xf   = (const float*)d_in[0];
  const float* xm   = (const float*)d_in[1];
  const float* xc   = (const float*)d_in[2];
  const float* pW0  = (const float*)d_in[3];
  const float* pb0  = (const float*)d_in[4];
  const float* pW1  = (const float*)d_in[5];
  const float* pb1  = (const float*)d_in[6];
  const float* pW2  = (const float*)d_in[7];
  const float* pb2  = (const float*)d_in[8];
  const float* rW1  = (const float*)d_in[9];
  const float* rb1  = (const float*)d_in[10];
  const float* rW2  = (const float*)d_in[11];
  const float* rb2  = (const float*)d_in[12];
  const float* lpW1 = (const float*)d_in[13];
  const float* lpb1 = (const float*)d_in[14];
  const float* lpW2 = (const float*)d_in[15];
  const float* lpb2 = (const float*)d_in[16];
  const float* lng  = (const float*)d_in[17];
  const float* lnb  = (const float*)d_in[18];
  const float* faW1 = (const float*)d_in[19];
  const float* fab1 = (const float*)d_in[20];
  const float* faW2 = (const float*)d_in[21];
  const float* fab2 = (const float*)d_in[22];
  const float* fng  = (const float*)d_in[23];
  const float* fnb  = (const float*)d_in[24];
  (void)in_sizes; (void)n_in; (void)out_size; (void)ws_size;

  bf16* ws = (bf16*)d_ws;
  float* out = (float*)d_out;

  wprep_kernel<<<204, 256, 0, stream>>>(pW0, pW1, pW2, rW1, lpW1, lpW2, faW1, faW2, ws);
  fused_kernel<<<1024, 256, 0, stream>>>(xf, xm, xc, pb0, pb1, pb2, rb1, rW2, rb2,
                                         lpb1, lpb2, lng, lnb, fab1, fab2, fng, fnb,
                                         ws, out);
}

// Round 6
// 434.238 us; speedup vs baseline: 1.5458x; 1.2129x over previous
//
#include <hip/hip_runtime.h>
#include <math.h>

typedef __bf16 bf16;
typedef __bf16 bf16x8 __attribute__((ext_vector_type(8)));
typedef __bf16 bf16x4 __attribute__((ext_vector_type(4)));
typedef float f32x4 __attribute__((ext_vector_type(4)));

#define B_ROWS 32768
#define PSZ 8192          // panel: 256 n-rows x 32 k, bf16 elems (16 KB)
#define PBYTES 16384

// panel-index bases in ws (panel-major, n-major within panel, UNSWIZZLED)
#define PB_PW0   0    // 4 panels  (K=128)
#define PB_PW1   4    // 8
#define PB_PW2   12   // 16
#define PB_RW1   28   // 6*16
#define PB_LPW1  124  // 3*8
#define PB_LPW2  148  // 3*8
#define PB_FAW1  172  // 24
#define PB_FAW2  196  // 8   (total 204 panels = 3.34 MB)

// Panel image: dst[n*32 + k'] = src[(kp*32 + k')*256 + n]  (fp32->bf16).
__global__ void wprep_kernel(const float* __restrict__ pW0, const float* __restrict__ pW1,
                             const float* __restrict__ pW2, const float* __restrict__ rW1,
                             const float* __restrict__ lpW1, const float* __restrict__ lpW2,
                             const float* __restrict__ faW1, const float* __restrict__ faW2,
                             bf16* __restrict__ ws) {
  int p = blockIdx.x;
  const float* src; int kp;
  if (p < 4)        { src = pW0;  kp = p; }
  else if (p < 12)  { src = pW1;  kp = p - 4; }
  else if (p < 28)  { src = pW2;  kp = p - 12; }
  else if (p < 124) { int q = p - 28;  src = rW1  + (size_t)(q >> 4) * 512 * 256; kp = q & 15; }
  else if (p < 148) { int q = p - 124; src = lpW1 + (size_t)(q >> 3) * 256 * 256; kp = q & 7; }
  else if (p < 172) { int q = p - 148; src = lpW2 + (size_t)(q >> 3) * 256 * 256; kp = q & 7; }
  else if (p < 196) { src = faW1; kp = p - 172; }
  else              { src = faW2; kp = p - 196; }
  bf16* dst = ws + (size_t)p * PSZ;
  int n = threadIdx.x;  // 256 threads, one n-row each
#pragma unroll
  for (int kb = 0; kb < 32; kb += 8) {
    bf16x8 v;
#pragma unroll
    for (int j = 0; j < 8; j++)
      v[j] = (bf16)src[(size_t)(kp * 32 + kb + j) * 256 + n];  // coalesced over n
    *(bf16x8*)(dst + n * 32 + kb) = v;
  }
}

#define FENCE asm volatile("" ::: "memory")
#define BAR()  do { FENCE; __builtin_amdgcn_s_barrier(); FENCE; } while (0)
#define BARP() do { asm volatile("s_waitcnt lgkmcnt(0)" ::: "memory"); \
                    __builtin_amdgcn_s_barrier(); FENCE; } while (0)
// Dataflow-tied counted waits (NO sched_barrier wall): the wait redefines the
// B slot it guards, so consuming MFMAs cannot hoist above it (rule #18), while
// the scheduler stays free to move independent work across the wait.
#define VWB2(N, B) asm volatile("s_waitcnt vmcnt(" #N ")" \
                                : "+v"(B[0]), "+v"(B[1]) :: "memory")
#define VWB4(N, B) asm volatile("s_waitcnt vmcnt(" #N ")" \
                                : "+v"(B[0]), "+v"(B[1]), "+v"(B[2]), "+v"(B[3]) :: "memory")

// 2 x global_load_dwordx4 of one 32-col B sub-panel into pinned registers.
__device__ __forceinline__ void ld2(bf16x8& d0, bf16x8& d1, const void* addr) {
  asm volatile("global_load_dwordx4 %0, %2, off\n\t"
               "global_load_dwordx4 %1, %2, off offset:1024"
               : "=&v"(d0), "=&v"(d1)
               : "v"(addr));
}
// 4 x global_load_dwordx4 of one 64-col B sub-panel into pinned registers.
__device__ __forceinline__ void ld4(bf16x8& d0, bf16x8& d1, bf16x8& d2, bf16x8& d3,
                                    const void* addr) {
  asm volatile("global_load_dwordx4 %0, %4, off\n\t"
               "global_load_dwordx4 %1, %4, off offset:1024\n\t"
               "global_load_dwordx4 %2, %4, off offset:2048\n\t"
               "global_load_dwordx4 %3, %4, off offset:3072"
               : "=&v"(d0), "=&v"(d1), "=&v"(d2), "=&v"(d3)
               : "v"(addr));
}

// R0 structure (64-row blocks, grid 512, 512 threads = 8 waves, 1 block/CU,
// proven 426us) with DEEPER B pipelines. Ledger (R1-R5): thinner blocks
// double the L2 weight stream (R5: +100us) -> row tile stays 64; any
// min-occupancy annotation >= 4 waves/EU makes the allocator spill at 64
// VGPR -> only amdgpu_waves_per_eu(2,2) is safe. At 1 block/CU (LDS 108KB)
// occupancy is LDS-capped at 2 waves/SIMD, so VGPR up to 256 is FREE:
// R0 used only 128 and stalled every phase on vmcnt (distance-2 pipe = 154
// cyc cover vs ~300 cyc L2 latency -> MfmaUtil 22%). This version: routing
// GEMM distance-4 (16 loads in flight, vmcnt(12)), narrow GEMMs distance-8
// (16 loads, vmcnt(14)), all buffers statically named (no dynamic indexing
// -> no scratch). Everything else byte-identical to R0.
__global__ void __launch_bounds__(512)
__attribute__((amdgpu_waves_per_eu(2, 2)))
fused_kernel(const float* __restrict__ xf, const float* __restrict__ xm,
                  const float* __restrict__ xc,
                  const float* __restrict__ pb0, const float* __restrict__ pb1v,
                  const float* __restrict__ pb2v,
                  const float* __restrict__ rb1, const float* __restrict__ rW2,
                  const float* __restrict__ rb2,
                  const float* __restrict__ lpb1, const float* __restrict__ lpb2,
                  const float* __restrict__ lng, const float* __restrict__ lnb,
                  const float* __restrict__ fab1, const float* __restrict__ fab2,
                  const float* __restrict__ fng, const float* __restrict__ fnb,
                  const bf16* __restrict__ ws, float* __restrict__ out) {
  __shared__ bf16 feats[3][64][256];   // 96 KB
  __shared__ bf16 apan[64][32];        // 4 KB (projection A staging)
  __shared__ float w_route[6][64];
  __shared__ float lnred[8][2][64];    // [cg][sum/sq][row]  4 KB

  const int t = threadIdx.x;
  const int lane = t & 63;
  const int cg = t >> 6;               // wave id, 0..7
  const int lr = lane & 15;
  const int lk = lane >> 4;
  const int r0 = blockIdx.x * 64;

  char* featsB = (char*)&feats[0][0][0];
  char* apanB  = (char*)&apan[0][0];

  f32x4 acc[16];  // merged routing: [rt*4+ct] rt<4,ct<4 ; narrow path: [rt*2+ct] ct<2
  auto zacc16 = [&]() {
#pragma unroll
    for (int i = 0; i < 16; i++) acc[i] = (f32x4){0.f, 0.f, 0.f, 0.f};
  };
  auto zacc8 = [&]() {
#pragma unroll
    for (int i = 0; i < 8; i++) acc[i] = (f32x4){0.f, 0.f, 0.f, 0.f};
  };

  auto mf = [&](bf16x8* Av, bf16x8* Bv) {   // 64x32 tile: 8 MFMA
    __builtin_amdgcn_s_setprio(1);
#pragma unroll
    for (int rt = 0; rt < 4; rt++)
#pragma unroll
      for (int ct = 0; ct < 2; ct++)
        acc[rt * 2 + ct] = __builtin_amdgcn_mfma_f32_16x16x32_bf16(Av[rt], Bv[ct], acc[rt * 2 + ct], 0, 0, 0);
    __builtin_amdgcn_s_setprio(0);
  };
  auto mfR = [&](bf16x8* Av, bf16x8* Bv) {  // 64x64 tile: 16 MFMA
    __builtin_amdgcn_s_setprio(1);
#pragma unroll
    for (int rt = 0; rt < 4; rt++)
#pragma unroll
      for (int ct = 0; ct < 4; ct++)
        acc[rt * 4 + ct] = __builtin_amdgcn_mfma_f32_16x16x32_bf16(Av[rt], Bv[ct], acc[rt * 4 + ct], 0, 0, 0);
    __builtin_amdgcn_s_setprio(0);
  };

  const int SRCa[6] = {0, 0, 1, 1, 2, 2};
  const int TGTa[6] = {1, 2, 0, 2, 0, 1};

  // Merged routing-pair GEMM (p0 even): n=16 phases, wave tile 64x64,
  // B distance-4 pinned (16 loads in flight, dataflow-tied vmcnt(12)).
  auto gemmR = [&](int p0) {
    const int pp = p0 + (cg >> 2);
    const char* Wb = (const char*)(ws + (size_t)(PB_RW1 + pp * 16) * PSZ)
                     + (((cg & 3) * 64 + lr) * 64 + lk * 16);
    const int lS = SRCa[p0];
    const int lT = TGTa[pp];
    bf16x8 Ba[4], Bb[4], Bc[4], Bd[4], Aa[4], Ab[4];
    auto ldB = [&](int s, bf16x8* Bv) {
      ld4(Bv[0], Bv[1], Bv[2], Bv[3], Wb + (size_t)s * PBYTES);
    };
    auto readA = [&](int s, bf16x8* Av) {
      int lvl = (s < 8) ? lS : lT;
      int q = (s & 7) * 4;
#pragma unroll
      for (int rt = 0; rt < 4; rt++) {
        int r = rt * 16 + lr;
        Av[rt] = *(const bf16x8*)(featsB + ((lvl * 64 + r) << 9) + (((q + lk) ^ (r & 7)) << 4));
      }
    };
    ldB(0, Ba); ldB(1, Bb); ldB(2, Bc); ldB(3, Bd);   // 16 loads in flight
    readA(0, Aa);
#pragma unroll 1
    for (int s = 0; s < 12; s += 4) {
      readA(s + 1, Ab); VWB4(12, Ba); mfR(Aa, Ba); ldB(s + 4, Ba);
      readA(s + 2, Aa); VWB4(12, Bb); mfR(Ab, Bb); ldB(s + 5, Bb);
      readA(s + 3, Ab); VWB4(12, Bc); mfR(Aa, Bc); ldB(s + 6, Bc);
      readA(s + 4, Aa); VWB4(12, Bd); mfR(Ab, Bd); ldB(s + 7, Bd);
    }
    // tail: phases 12..15
    readA(13, Ab); VWB4(12, Ba); mfR(Aa, Ba);
    readA(14, Aa); VWB4(8, Bb);  mfR(Ab, Bb);
    readA(15, Ab); VWB4(4, Bc);  mfR(Aa, Bc);
    VWB4(0, Bd); mfR(Ab, Bd);
  };

  // Merged routing epilogue: produces gates for p0 (waves 0-3) and p0+1 (4-7).
  auto routing_epi2 = [&](int p0) {
    const int pp = p0 + (cg >> 2);
    float part[4][4] = {{0}};
#pragma unroll
    for (int ct = 0; ct < 4; ct++) {
      int col = (cg & 3) * 64 + ct * 16 + lr;
      float b1 = rb1[pp * 256 + col];
      float w2 = rW2[pp * 256 + col];
#pragma unroll
      for (int rt = 0; rt < 4; rt++)
#pragma unroll
        for (int e = 0; e < 4; e++)
          part[rt][e] += fmaxf(acc[rt * 4 + ct][e] + b1, 0.f) * w2;
    }
#pragma unroll
    for (int m = 1; m < 16; m <<= 1)
#pragma unroll
      for (int rt = 0; rt < 4; rt++)
#pragma unroll
        for (int e = 0; e < 4; e++)
          part[rt][e] += __shfl_xor(part[rt][e], m, 64);
    if (lr == 0)
#pragma unroll
      for (int rt = 0; rt < 4; rt++)
#pragma unroll
        for (int e = 0; e < 4; e++)
          lnred[cg][0][rt * 16 + lk * 4 + e] = part[rt][e];
    BARP();
    if (t < 128) {
      int pi = t >> 6, r = t & 63;
      float s = rb2[p0 + pi];
#pragma unroll
      for (int g = 0; g < 4; g++) s += lnred[pi * 4 + g][0][r];
      w_route[p0 + pi][r] = 1.f / (1.f + expf(-s));
    }
    BARP();
  };

  // Narrow GEMM, n=8 (lp/fa2): wave tile 64x32, B distance-8 pinned.
  // All 16 loads issued up front; dataflow-tied decreasing vmcnt.
  auto gemm8 = [&](const char* Wb0, int lvl) {
    const char* Wb = Wb0 + ((cg * 32 + lr) * 64 + lk * 16);
    bf16x8 B0[2], B1[2], B2[2], B3[2], B4[2], B5[2], B6[2], B7[2], Aa[4], Ab[4];
    auto readA = [&](int s, bf16x8* Av) {
      int q = (s & 7) * 4;
#pragma unroll
      for (int rt = 0; rt < 4; rt++) {
        int r = rt * 16 + lr;
        Av[rt] = *(const bf16x8*)(featsB + ((lvl * 64 + r) << 9) + (((q + lk) ^ (r & 7)) << 4));
      }
    };
    ld2(B0[0], B0[1], Wb + (size_t)0 * PBYTES);
    ld2(B1[0], B1[1], Wb + (size_t)1 * PBYTES);
    ld2(B2[0], B2[1], Wb + (size_t)2 * PBYTES);
    ld2(B3[0], B3[1], Wb + (size_t)3 * PBYTES);
    ld2(B4[0], B4[1], Wb + (size_t)4 * PBYTES);
    ld2(B5[0], B5[1], Wb + (size_t)5 * PBYTES);
    ld2(B6[0], B6[1], Wb + (size_t)6 * PBYTES);
    ld2(B7[0], B7[1], Wb + (size_t)7 * PBYTES);   // 16 loads in flight
    readA(0, Aa);
    readA(1, Ab); VWB2(14, B0); mf(Aa, B0);
    readA(2, Aa); VWB2(12, B1); mf(Ab, B1);
    readA(3, Ab); VWB2(10, B2); mf(Aa, B2);
    readA(4, Aa); VWB2(8, B3);  mf(Ab, B3);
    readA(5, Ab); VWB2(6, B4);  mf(Aa, B4);
    readA(6, Aa); VWB2(4, B5);  mf(Ab, B5);
    readA(7, Ab); VWB2(2, B6);  mf(Aa, B6);
    VWB2(0, B7); mf(Ab, B7);
  };

  // Narrow GEMM, n=24 (fa1, A levels 0/1/2 per 8-phase chunk): distance-8,
  // steady vmcnt(14), fully unrolled so buffer names stay static.
  auto gemm24 = [&](const char* Wb0) {
    const char* Wb = Wb0 + ((cg * 32 + lr) * 64 + lk * 16);
    bf16x8 B0[2], B1[2], B2[2], B3[2], B4[2], B5[2], B6[2], B7[2], Aa[4], Ab[4];
    auto readA = [&](int s, bf16x8* Av) {
      int lvl = s >> 3;
      int q = (s & 7) * 4;
#pragma unroll
      for (int rt = 0; rt < 4; rt++) {
        int r = rt * 16 + lr;
        Av[rt] = *(const bf16x8*)(featsB + ((lvl * 64 + r) << 9) + (((q + lk) ^ (r & 7)) << 4));
      }
    };
    ld2(B0[0], B0[1], Wb + (size_t)0 * PBYTES);
    ld2(B1[0], B1[1], Wb + (size_t)1 * PBYTES);
    ld2(B2[0], B2[1], Wb + (size_t)2 * PBYTES);
    ld2(B3[0], B3[1], Wb + (size_t)3 * PBYTES);
    ld2(B4[0], B4[1], Wb + (size_t)4 * PBYTES);
    ld2(B5[0], B5[1], Wb + (size_t)5 * PBYTES);
    ld2(B6[0], B6[1], Wb + (size_t)6 * PBYTES);
    ld2(B7[0], B7[1], Wb + (size_t)7 * PBYTES);   // 16 loads in flight
    readA(0, Aa);
#pragma unroll
    for (int blk = 0; blk < 2; blk++) {
      int s0 = blk * 8;
      readA(s0 + 1, Ab); VWB2(14, B0); mf(Aa, B0); ld2(B0[0], B0[1], Wb + (size_t)(s0 + 8) * PBYTES);
      readA(s0 + 2, Aa); VWB2(14, B1); mf(Ab, B1); ld2(B1[0], B1[1], Wb + (size_t)(s0 + 9) * PBYTES);
      readA(s0 + 3, Ab); VWB2(14, B2); mf(Aa, B2); ld2(B2[0], B2[1], Wb + (size_t)(s0 + 10) * PBYTES);
      readA(s0 + 4, Aa); VWB2(14, B3); mf(Ab, B3); ld2(B3[0], B3[1], Wb + (size_t)(s0 + 11) * PBYTES);
      readA(s0 + 5, Ab); VWB2(14, B4); mf(Aa, B4); ld2(B4[0], B4[1], Wb + (size_t)(s0 + 12) * PBYTES);
      readA(s0 + 6, Aa); VWB2(14, B5); mf(Ab, B5); ld2(B5[0], B5[1], Wb + (size_t)(s0 + 13) * PBYTES);
      readA(s0 + 7, Ab); VWB2(14, B6); mf(Aa, B6); ld2(B6[0], B6[1], Wb + (size_t)(s0 + 14) * PBYTES);
      readA(s0 + 8, Aa); VWB2(14, B7); mf(Ab, B7); ld2(B7[0], B7[1], Wb + (size_t)(s0 + 15) * PBYTES);
    }
    // tail: phases 16..23
    readA(17, Ab); VWB2(14, B0); mf(Aa, B0);
    readA(18, Aa); VWB2(12, B1); mf(Ab, B1);
    readA(19, Ab); VWB2(10, B2); mf(Aa, B2);
    readA(20, Aa); VWB2(8, B3);  mf(Ab, B3);
    readA(21, Ab); VWB2(6, B4);  mf(Aa, B4);
    readA(22, Aa); VWB2(4, B5);  mf(Ab, B5);
    readA(23, Ab); VWB2(2, B6);  mf(Aa, B6);
    VWB2(0, B7); mf(Ab, B7);
  };

  // Projection GEMM: A = x (fp32 global) staged through apan; B direct.
  auto gemm_x = [&](const bf16* W, int n, const float* X, int Kx) {
    const char* Wb = (const char*)W + ((cg * 32 + lr) * 64 + lk * 16);
#pragma unroll 1
    for (int s = 0; s < n; s++) {
      bf16x8 b[2];
#pragma unroll
      for (int ct = 0; ct < 2; ct++)
        b[ct] = *(const bf16x8*)(Wb + (size_t)s * PBYTES + ct * 1024);
      int rr = t >> 3, c0 = (t & 7) * 4;
      float4 xv = *(const float4*)(X + (size_t)(r0 + rr) * Kx + s * 32 + c0);
      BAR();
      bf16x4 v;
      v[0] = (bf16)xv.x; v[1] = (bf16)xv.y; v[2] = (bf16)xv.z; v[3] = (bf16)xv.w;
      int cb = c0 >> 3;
      *(bf16x4*)(apanB + (rr << 6) + ((cb ^ ((rr >> 1) & 3)) << 4) + (c0 & 7) * 2) = v;
      BARP();
      bf16x8 a[4];
#pragma unroll
      for (int rt = 0; rt < 4; rt++) {
        int r = rt * 16 + lr;
        a[rt] = *(const bf16x8*)(apanB + (r << 6) + ((lk ^ ((r >> 1) & 3)) << 4));
      }
      mf(a, b);
    }
  };

  auto stF = [&](int lvl, int r, int c, float v) {
    *(bf16*)(featsB + ((lvl * 64 + r) << 9) +
             ((((c >> 3) ^ (r & 7))) << 4) + (c & 7) * 2) = (bf16)v;
  };
  auto epi_bias_store = [&](const float* bias, int lvl, bool do_relu) {
    BAR();
#pragma unroll
    for (int ct = 0; ct < 2; ct++) {
      int col = cg * 32 + ct * 16 + lr;
      float bv = bias[col];
#pragma unroll
      for (int rt = 0; rt < 4; rt++)
#pragma unroll
        for (int e = 0; e < 4; e++) {
          float v = acc[rt * 2 + ct][e] + bv;
          if (do_relu) v = fmaxf(v, 0.f);
          stF(lvl, rt * 16 + lk * 4 + e, col, v);
        }
    }
    BARP();
  };
  auto ln_epi = [&](const float* bias, const float* gamma, const float* beta, int lvl) {
    float sum[4][4] = {{0}}, sq[4][4] = {{0}};
#pragma unroll
    for (int ct = 0; ct < 2; ct++) {
      int col = cg * 32 + ct * 16 + lr;
      float bv = bias[col];
#pragma unroll
      for (int rt = 0; rt < 4; rt++)
#pragma unroll
        for (int e = 0; e < 4; e++) {
          float v = acc[rt * 2 + ct][e] + bv;
          acc[rt * 2 + ct][e] = v;
          sum[rt][e] += v; sq[rt][e] += v * v;
        }
    }
#pragma unroll
    for (int m = 1; m < 16; m <<= 1)
#pragma unroll
      for (int rt = 0; rt < 4; rt++)
#pragma unroll
      for (int e = 0; e < 4; e++) {
          sum[rt][e] += __shfl_xor(sum[rt][e], m, 64);
          sq[rt][e]  += __shfl_xor(sq[rt][e], m, 64);
        }
    if (lr == 0)
#pragma unroll
      for (int rt = 0; rt < 4; rt++)
#pragma unroll
        for (int e = 0; e < 4; e++) {
          int r = rt * 16 + lk * 4 + e;
          lnred[cg][0][r] = sum[rt][e];
          lnred[cg][1][r] = sq[rt][e];
        }
    BARP();
    if (t < 64) {
      float su = 0.f, sz = 0.f;
#pragma unroll
      for (int g = 0; g < 8; g++) { su += lnred[g][0][t]; sz += lnred[g][1][t]; }
      float mu = su * (1.f / 256.f);
      float ms = sz * (1.f / 256.f);
      lnred[0][0][t] = mu;
      lnred[0][1][t] = rsqrtf(ms - mu * mu + 1e-5f);
    }
    BARP();
#pragma unroll
    for (int rt = 0; rt < 4; rt++)
#pragma unroll
      for (int e = 0; e < 4; e++) {
        int r = rt * 16 + lk * 4 + e;
        float mu = lnred[0][0][r];
        float rstd = lnred[0][1][r];
#pragma unroll
        for (int ct = 0; ct < 2; ct++) {
          int col = cg * 32 + ct * 16 + lr;
          float v = (acc[rt * 2 + ct][e] - mu) * rstd * gamma[col] + beta[col];
          if (lvl >= 0) stF(lvl, r, col, v);
          else out[(size_t)(r0 + r) * 256 + col] = v;
        }
      }
    BARP();
  };

  // ---------------- schedule ----------------
  zacc8(); gemm_x(ws + PB_PW0 * PSZ, 4,  xf, 128); epi_bias_store(pb0, 0, false);
  zacc8(); gemm_x(ws + PB_PW1 * PSZ, 8,  xm, 256); epi_bias_store(pb1v, 1, false);
  zacc8(); gemm_x(ws + PB_PW2 * PSZ, 16, xc, 512); epi_bias_store(pb2v, 2, false);

  for (int it = 0; it < 3; it++) {
    for (int p0 = 0; p0 < 6; p0 += 2) {
      zacc16();
      gemmR(p0);
      routing_epi2(p0);
    }
    // upd = feats + segment_sum(w * src)  (in place, disjoint per thread)
    {
      int r = t >> 3, c0 = (t & 7) * 32;
      float w6[6];
#pragma unroll
      for (int p = 0; p < 6; p++) w6[p] = w_route[p][r];
#pragma unroll
      for (int ccx = 0; ccx < 32; ccx += 8) {
        int c = c0 + ccx;
        int chunk = (((c >> 3) ^ (r & 7)) << 4);
        char* a0 = featsB + ((0 * 64 + r) << 9) + chunk;
        char* a1 = featsB + ((1 * 64 + r) << 9) + chunk;
        char* a2 = featsB + ((2 * 64 + r) << 9) + chunk;
        bf16x8 f0 = *(bf16x8*)a0, f1 = *(bf16x8*)a1, f2 = *(bf16x8*)a2;
        bf16x8 u0, u1, u2;
#pragma unroll
        for (int i = 0; i < 8; i++) {
          float a = (float)f0[i], b = (float)f1[i], d = (float)f2[i];
          u0[i] = (bf16)(a + w6[2] * b + w6[4] * d);
          u1[i] = (bf16)(b + w6[0] * a + w6[5] * d);
          u2[i] = (bf16)(d + w6[1] * a + w6[3] * b);
        }
        *(bf16x8*)a0 = u0; *(bf16x8*)a1 = u1; *(bf16x8*)a2 = u2;
      }
      BARP();
    }
    for (int l = 0; l < 3; l++) {
      zacc8();
      gemm8((const char*)(ws + (size_t)(PB_LPW1 + l * 8) * PSZ), l);
      epi_bias_store(lpb1 + l * 256, l, true);
      zacc8();
      gemm8((const char*)(ws + (size_t)(PB_LPW2 + l * 8) * PSZ), l);
      ln_epi(lpb2 + l * 256, lng + l * 256, lnb + l * 256, l);
    }
  }

  zacc8();
  gemm24((const char*)(ws + (size_t)PB_FAW1 * PSZ));
  epi_bias_store(fab1, 0, true);   // h4 -> feats[0] (feats dead)
  zacc8();
  gemm8((const char*)(ws + (size_t)PB_FAW2 * PSZ), 0);
  ln_epi(fab2, fng, fnb, -1);

  // w output (last iteration's gates): out[B*256 + p*B + row]
  if (t < 384) {
    int p = t >> 6, r = t & 63;
    out[(size_t)B_ROWS * 256 + (size_t)p * B_ROWS + r0 + r] = w_route[p][r];
  }
}

extern "C" void kernel_launch(void* const* d_in, const int* in_sizes, int n_in,
                              void* d_out, int out_size, void* d_ws, size_t ws_size,
                              hipStream_t stream) {
  const float* xf   = (const float*)d_in[0];
  const float* xm   = (const float*)d_in[1];
  const float* xc   = (const float*)d_in[2];
  const float* pW0  = (const float*)d_in[3];
  const float* pb0  = (const float*)d_in[4];
  const float* pW1  = (const float*)d_in[5];
  const float* pb1  = (const float*)d_in[6];
  const float* pW2  = (const float*)d_in[7];
  const float* pb2  = (const float*)d_in[8];
  const float* rW1  = (const float*)d_in[9];
  const float* rb1  = (const float*)d_in[10];
  const float* rW2  = (const float*)d_in[11];
  const float* rb2  = (const float*)d_in[12];
  const float* lpW1 = (const float*)d_in[13];
  const float* lpb1 = (const float*)d_in[14];
  const float* lpW2 = (const float*)d_in[15];
  const float* lpb2 = (const float*)d_in[16];
  const float* lng  = (const float*)d_in[17];
  const float* lnb  = (const float*)d_in[18];
  const float* faW1 = (const float*)d_in[19];
  const float* fab1 = (const float*)d_in[20];
  const float* faW2 = (const float*)d_in[21];
  const float* fab2 = (const float*)d_in[22];
  const float* fng  = (const float*)d_in[23];
  const float* fnb  = (const float*)d_in[24];
  (void)in_sizes; (void)n_in; (void)out_size; (void)ws_size;

  bf16* ws = (bf16*)d_ws;
  float* out = (float*)d_out;

  wprep_kernel<<<204, 256, 0, stream>>>(pW0, pW1, pW2, rW1, lpW1, lpW2, faW1, faW2, ws);
  fused_kernel<<<512, 512, 0, stream>>>(xf, xm, xc, pb0, pb1, pb2, rb1, rW2, rb2,
                                        lpb1, lpb2, lng, lnb, fab1, fab2, fng, fnb,
                                        ws, out);
}